// Round 2
// baseline (555.906 us; speedup 1.0000x reference)
//
#include <hip/hip_runtime.h>
#include <hip/hip_bf16.h>

#define N_NODES 50000
#define N_EDGES 800000

typedef __attribute__((ext_vector_type(8))) short bf16x8;
typedef __attribute__((ext_vector_type(4))) float f32x4;

__device__ __forceinline__ float bf2f(unsigned short u) {
    unsigned int x = ((unsigned int)u) << 16;
    return __uint_as_float(x);
}
__device__ __forceinline__ unsigned short f2bf(float f) {
    unsigned int x = __float_as_uint(f);
    unsigned int lsb = (x >> 16) & 1u;
    x += 0x7fffu + lsb;
    return (unsigned short)(x >> 16);
}

// ---------------- CSR build ----------------

__global__ void k_zero(int* p, int n) {
    int i = blockIdx.x * blockDim.x + threadIdx.x;
    if (i < n) p[i] = 0;
}

__global__ void k_deg(const int* __restrict__ dst, int* __restrict__ deg) {
    int e = blockIdx.x * blockDim.x + threadIdx.x;
    if (e < N_EDGES) atomicAdd(&deg[dst[e]], 1);
}

// single-block exclusive scan over deg -> offsets[0..N], plus pos copy and inv_deg
__global__ void k_scan(const int* __restrict__ deg, int* __restrict__ offsets,
                       int* __restrict__ pos, float* __restrict__ inv_deg) {
    __shared__ int buf[1024];
    __shared__ int carry_s;
    int tid = threadIdx.x;
    if (tid == 0) carry_s = 0;
    __syncthreads();
    for (int base = 0; base < N_NODES; base += 1024) {
        int idx = base + tid;
        int v = (idx < N_NODES) ? deg[idx] : 0;
        buf[tid] = v;
        __syncthreads();
        for (int off = 1; off < 1024; off <<= 1) {
            int t = (tid >= off) ? buf[tid - off] : 0;
            __syncthreads();
            buf[tid] += t;
            __syncthreads();
        }
        int incl = buf[tid];
        int c = carry_s;
        if (idx < N_NODES) {
            int excl = c + incl - v;
            offsets[idx] = excl;
            pos[idx] = excl;
            inv_deg[idx] = 1.0f / (float)max(v, 1);
        }
        __syncthreads();
        if (tid == 1023) carry_s = c + incl;
        __syncthreads();
    }
    if (tid == 0) offsets[N_NODES] = carry_s;
}

__global__ void k_scatter(const int* __restrict__ src, const int* __restrict__ dst,
                          int* __restrict__ pos, int* __restrict__ edge_src) {
    int e = blockIdx.x * blockDim.x + threadIdx.x;
    if (e < N_EDGES) {
        int p = atomicAdd(&pos[dst[e]], 1);
        edge_src[p] = src[e];
    }
}

// ---------------- mean aggregation (one wave per node) ----------------
// IN_FP32: h is [N,128] fp32; lane i handles cols {2i, 2i+1} via float2 (512B/row/wave).
// else:    h is [N,128] bf16; lane i reads one packed uint (256B/row/wave).
// msg out: [N,128] bf16 (packed uint per lane). fp32 accumulation.
template <bool IN_FP32>
__global__ void k_agg(const void* __restrict__ hv, const int* __restrict__ offsets,
                      const int* __restrict__ edge_src, const float* __restrict__ inv_deg,
                      __hip_bfloat16* __restrict__ msg) {
    int gid = blockIdx.x * blockDim.x + threadIdx.x;
    int node = gid >> 6;
    int lane = gid & 63;
    if (node >= N_NODES) return;
    int beg = offsets[node], end = offsets[node + 1];
    float a0 = 0.f, a1 = 0.f;
    if (IN_FP32) {
        const float2* hp = (const float2*)hv;  // 64 float2 per row
        for (int i = beg; i < end; ++i) {
            int s = edge_src[i];
            float2 u = hp[(size_t)s * 64 + lane];
            a0 += u.x;
            a1 += u.y;
        }
    } else {
        const unsigned int* hp = (const unsigned int*)hv;  // 64 uints per row
        for (int i = beg; i < end; ++i) {
            int s = edge_src[i];
            unsigned int u = hp[(size_t)s * 64 + lane];
            a0 += bf2f((unsigned short)(u & 0xffffu));
            a1 += bf2f((unsigned short)(u >> 16));
        }
    }
    float w = inv_deg[node];
    unsigned int packed = ((unsigned int)f2bf(a1 * w) << 16) | (unsigned int)f2bf(a0 * w);
    ((unsigned int*)msg)[(size_t)node * 64 + lane] = packed;
}

// ---------------- W fragment packing (fp32 weights -> bf16 B-fragments) ----------------
// Bcat[k][n], k in [0,256): k<128 -> Wself[k][n], else Wneigh[k-128][n]. W row-major [128][Dout].
// frag: lane of (ct,kt) holds B[kt*32 + (lane>>4)*8 + j][ct*16 + (lane&15)], j=0..7.
__global__ void k_wprep(const float* __restrict__ Wself, const float* __restrict__ Wneigh,
                        int Dout, __hip_bfloat16* __restrict__ frag) {
    int t = blockIdx.x * blockDim.x + threadIdx.x;
    int nCt = Dout >> 4;
    int total = nCt * 8 * 64;
    if (t >= total) return;
    int lane = t & 63;
    int kt = (t >> 6) & 7;
    int ct = t >> 9;
    int q = lane >> 4;
    int n = ct * 16 + (lane & 15);
    unsigned short* dstp = (unsigned short*)frag + ((size_t)((ct * 8 + kt) * 64 + lane)) * 8;
    #pragma unroll
    for (int j = 0; j < 8; ++j) {
        int k = kt * 32 + q * 8 + j;
        float v = (k < 128) ? Wself[k * Dout + n] : Wneigh[(k - 128) * Dout + n];
        dstp[j] = f2bf(v);
    }
}

// ---------------- fused GEMM + bias (+ relu + l2norm) ----------------
// out[n][:] = epilogue( Aself[n]@Wself + Aneigh[n]@Wneigh + b ), K=256 fused via MFMA.
// Block = 256 threads = 4 waves; wave handles 16 rows x Dout cols.
// SELF_FP32: Aself is fp32 [N,128] (converted inline); else bf16. Aneigh always bf16.
// LAST: no relu/l2norm, output fp32; else output bf16.
template <int NCT, bool LAST, bool SELF_FP32>
__global__ __launch_bounds__(256) void k_gemm(const void* __restrict__ Aself_,
                                              const __hip_bfloat16* __restrict__ Aneigh,
                                              const __hip_bfloat16* __restrict__ frag,
                                              const float* __restrict__ bias,
                                              void* __restrict__ out_) {
    constexpr int Dout = NCT * 16;
    int tid = threadIdx.x;
    int wv = tid >> 6, lane = tid & 63;
    int n0 = blockIdx.x * 64 + wv * 16;
    if (n0 >= N_NODES) return;  // wave-uniform early exit, no LDS used
    int q = lane >> 4, l15 = lane & 15;
    int rowA = n0 + l15;
    if (rowA > N_NODES - 1) rowA = N_NODES - 1;  // clamp loads; stores guarded below

    f32x4 acc[NCT];
    #pragma unroll
    for (int c = 0; c < NCT; ++c) acc[c] = (f32x4){0.f, 0.f, 0.f, 0.f};

    const bf16x8* fragv = (const bf16x8*)frag;
    #pragma unroll
    for (int kt = 0; kt < 8; ++kt) {
        int kb = (kt & 3) * 32 + q * 8;
        bf16x8 a;
        if (kt < 4) {
            if (SELF_FP32) {
                const float* Af = (const float*)Aself_ + (size_t)rowA * 128 + kb;
                #pragma unroll
                for (int j = 0; j < 8; ++j) ((unsigned short*)&a)[j] = f2bf(Af[j]);
            } else {
                a = *(const bf16x8*)((const __hip_bfloat16*)Aself_ + (size_t)rowA * 128 + kb);
            }
        } else {
            a = *(const bf16x8*)(Aneigh + (size_t)rowA * 128 + kb);
        }
        #pragma unroll
        for (int ct = 0; ct < NCT; ++ct) {
            bf16x8 b = fragv[(ct * 8 + kt) * 64 + lane];
            acc[ct] = __builtin_amdgcn_mfma_f32_16x16x32_bf16(a, b, acc[ct], 0, 0, 0);
        }
    }

    float ss[4] = {0.f, 0.f, 0.f, 0.f};
    #pragma unroll
    for (int ct = 0; ct < NCT; ++ct) {
        float bc = bias[ct * 16 + l15];
        #pragma unroll
        for (int r = 0; r < 4; ++r) {
            float v = acc[ct][r] + bc;
            if (!LAST) v = fmaxf(v, 0.0f);
            acc[ct][r] = v;
            ss[r] += v * v;
        }
    }

    float scale[4];
    #pragma unroll
    for (int r = 0; r < 4; ++r) {
        if (!LAST) {
            float s = ss[r];
            s += __shfl_xor(s, 1);
            s += __shfl_xor(s, 2);
            s += __shfl_xor(s, 4);
            s += __shfl_xor(s, 8);
            scale[r] = 1.0f / fmaxf(sqrtf(s), 1e-12f);
        } else {
            scale[r] = 1.0f;
        }
    }

    #pragma unroll
    for (int ct = 0; ct < NCT; ++ct) {
        #pragma unroll
        for (int r = 0; r < 4; ++r) {
            int row = n0 + q * 4 + r;
            if (row < N_NODES) {
                float v = acc[ct][r] * scale[r];
                if (LAST)
                    ((float*)out_)[(size_t)row * Dout + ct * 16 + l15] = v;
                else
                    ((unsigned short*)out_)[(size_t)row * Dout + ct * 16 + l15] = f2bf(v);
            }
        }
    }
}

// ---------------- host launch ----------------

extern "C" void kernel_launch(void* const* d_in, const int* in_sizes, int n_in,
                              void* d_out, int out_size, void* d_ws, size_t ws_size,
                              hipStream_t stream) {
    const float* features = (const float*)d_in[0];
    const int* src = (const int*)d_in[1];
    const int* dst = (const int*)d_in[2];
    const float* Ws0 = (const float*)d_in[3];
    const float* Wn0 = (const float*)d_in[4];
    const float* b0  = (const float*)d_in[5];
    const float* Ws1 = (const float*)d_in[6];
    const float* Wn1 = (const float*)d_in[7];
    const float* b1  = (const float*)d_in[8];
    const float* Ws2 = (const float*)d_in[9];
    const float* Wn2 = (const float*)d_in[10];
    const float* b2  = (const float*)d_in[11];
    float* out = (float*)d_out;

    char* ws = (char*)d_ws;
    size_t off = 0;
    auto alloc = [&](size_t bytes) -> void* {
        void* p = ws + off;
        off = (off + bytes + 255) & ~(size_t)255;
        return p;
    };
    int*   deg      = (int*)alloc((size_t)N_NODES * 4);
    int*   offs     = (int*)alloc((size_t)(N_NODES + 1) * 4);
    int*   pos      = (int*)alloc((size_t)N_NODES * 4);
    int*   edge_src = (int*)alloc((size_t)N_EDGES * 4);
    float* inv_deg  = (float*)alloc((size_t)N_NODES * 4);
    __hip_bfloat16* msg = (__hip_bfloat16*)alloc((size_t)N_NODES * 128 * 2);
    __hip_bfloat16* h1  = (__hip_bfloat16*)alloc((size_t)N_NODES * 128 * 2);
    __hip_bfloat16* h2  = (__hip_bfloat16*)alloc((size_t)N_NODES * 128 * 2);
    __hip_bfloat16* frag0 = (__hip_bfloat16*)alloc((size_t)8 * 8 * 64 * 8 * 2);
    __hip_bfloat16* frag1 = (__hip_bfloat16*)alloc((size_t)8 * 8 * 64 * 8 * 2);
    __hip_bfloat16* frag2 = (__hip_bfloat16*)alloc((size_t)4 * 8 * 64 * 8 * 2);

    // CSR build
    k_zero<<<(N_NODES + 255) / 256, 256, 0, stream>>>(deg, N_NODES);
    k_deg<<<(N_EDGES + 255) / 256, 256, 0, stream>>>(dst, deg);
    k_scan<<<1, 1024, 0, stream>>>(deg, offs, pos, inv_deg);
    k_scatter<<<(N_EDGES + 255) / 256, 256, 0, stream>>>(src, dst, pos, edge_src);

    // W fragment packing
    k_wprep<<<16, 256, 0, stream>>>(Ws0, Wn0, 128, frag0);
    k_wprep<<<16, 256, 0, stream>>>(Ws1, Wn1, 128, frag1);
    k_wprep<<<8, 256, 0, stream>>>(Ws2, Wn2, 64, frag2);

    const int aggGrid = (N_NODES * 64) / 256;  // 12500
    const int gemmGrid = (N_NODES + 63) / 64;  // 782

    // Layer 1
    k_agg<true><<<aggGrid, 256, 0, stream>>>(features, offs, edge_src, inv_deg, msg);
    k_gemm<8, false, true><<<gemmGrid, 256, 0, stream>>>(features, msg, frag0, b0, h1);
    // Layer 2
    k_agg<false><<<aggGrid, 256, 0, stream>>>(h1, offs, edge_src, inv_deg, msg);
    k_gemm<8, false, false><<<gemmGrid, 256, 0, stream>>>(h1, msg, frag1, b1, h2);
    // Layer 3
    k_agg<false><<<aggGrid, 256, 0, stream>>>(h2, offs, edge_src, inv_deg, msg);
    k_gemm<4, true, false><<<gemmGrid, 256, 0, stream>>>(h2, msg, frag2, b2, out);
}